// Round 14
// baseline (370.381 us; speedup 1.0000x reference)
//
#include <hip/hip_runtime.h>
#include <hip/hip_bf16.h>
#include <math.h>

typedef unsigned short ush;
typedef __attribute__((ext_vector_type(8))) short frag16;   // 8 bf16 = 4 VGPRs
typedef __attribute__((ext_vector_type(4))) float f32x4;

#define S_   1024
#define H_   1024
#define NH_  16
#define D_   64
#define L_   9
#define MB_  (1048576ull)

__device__ __forceinline__ ush bf16_rne(float x) {
  unsigned int b = __float_as_uint(x);
  b += 0x7FFFu + ((b >> 16) & 1u);
  return (ush)(b >> 16);
}
__device__ __forceinline__ void split2(float x, ush& h, ush& l) {
  h = bf16_rne(x);
  l = bf16_rne(x - __uint_as_float((unsigned int)h << 16));
}

// ---------------------------------------------------------------------------
// Split + transpose 4 weights in one launch. (verified R10)
// ---------------------------------------------------------------------------
__global__ __launch_bounds__(256) void split_wT4(
    const float* W0, const float* W1, const float* W2, const float* W3,
    ush* h0, ush* l0, ush* h1, ush* l1, ush* h2, ush* l2, ush* h3, ush* l3) {
  __shared__ __align__(16) float Ls[64][68];
  const float* W = (blockIdx.z == 0) ? W0 : (blockIdx.z == 1) ? W1
                 : (blockIdx.z == 2) ? W2 : W3;
  ush* Th = (blockIdx.z == 0) ? h0 : (blockIdx.z == 1) ? h1
          : (blockIdx.z == 2) ? h2 : h3;
  ush* Tl = (blockIdx.z == 0) ? l0 : (blockIdx.z == 1) ? l1
          : (blockIdx.z == 2) ? l2 : l3;
  const int tid = threadIdx.x;
  const int n0 = blockIdx.x * 64, k0 = blockIdx.y * 64;
#pragma unroll
  for (int it = 0; it < 4; it++) {
    int flat = tid + 256 * it;
    int row = flat >> 4, nc = (flat & 15) * 4;
    *(float4*)&Ls[row][nc] = *(const float4*)&W[(size_t)(k0 + row) * 1024 + n0 + nc];
  }
  __syncthreads();
#pragma unroll
  for (int it = 0; it < 2; it++) {
    int flat = tid + 256 * it;
    int nrow = flat >> 3, kc = (flat & 7) * 8;
    ush hs[8], ls[8];
#pragma unroll
    for (int u = 0; u < 8; u++) split2(Ls[kc + u][nrow], hs[u], ls[u]);
    uint4 ph, pl;
    ph.x = hs[0] | ((unsigned)hs[1] << 16); ph.y = hs[2] | ((unsigned)hs[3] << 16);
    ph.z = hs[4] | ((unsigned)hs[5] << 16); ph.w = hs[6] | ((unsigned)hs[7] << 16);
    pl.x = ls[0] | ((unsigned)ls[1] << 16); pl.y = ls[2] | ((unsigned)ls[3] << 16);
    pl.z = ls[4] | ((unsigned)ls[5] << 16); pl.w = ls[6] | ((unsigned)ls[7] << 16);
    size_t o = (size_t)(n0 + nrow) * 1024 + k0 + kc;
    *(uint4*)&Th[o] = ph;
    *(uint4*)&Tl[o] = pl;
  }
}

// ---------------------------------------------------------------------------
// Pre-split x (verified R13, bitwise = in-loop split).
// ---------------------------------------------------------------------------
__global__ __launch_bounds__(256) void split_x(
    const float* __restrict__ x, ush* __restrict__ xh, ush* __restrict__ xl) {
  const size_t i = ((size_t)blockIdx.x * 256 + threadIdx.x) * 8;
  float4 a = *(const float4*)&x[i];
  float4 b = *(const float4*)&x[i + 4];
  const float v[8] = {a.x, a.y, a.z, a.w, b.x, b.y, b.z, b.w};
  ush h[8], l[8];
#pragma unroll
  for (int u = 0; u < 8; u++) split2(v[u], h[u], l[u]);
  uint4 ph, pl;
  ph.x = h[0] | ((unsigned)h[1] << 16); ph.y = h[2] | ((unsigned)h[3] << 16);
  ph.z = h[4] | ((unsigned)h[5] << 16); ph.w = h[6] | ((unsigned)h[7] << 16);
  pl.x = l[0] | ((unsigned)l[1] << 16); pl.y = l[2] | ((unsigned)l[3] << 16);
  pl.z = l[4] | ((unsigned)l[5] << 16); pl.w = l[6] | ((unsigned)l[7] << 16);
  *(uint4*)&xh[i] = ph;
  *(uint4*)&xl[i] = pl;
}

// ---------------------------------------------------------------------------
// Fused q+k split-bf16 MFMA GEMM. Grid (16,64): bx>>3 selects weight set
// (0=q, 1=k), n0 = (bx&7)*128. 1024 blocks = 4/CU co-resident (vs 2 for the
// separate 512-block launches). Per-tile math identical to gemm_mn EP0 ->
// bitwise-neutral. LDS 30,720 B.
// ---------------------------------------------------------------------------
__global__ __launch_bounds__(256) void gemm_qk(
    const ush* __restrict__ xh, const ush* __restrict__ xl,
    const ush* __restrict__ Wqh, const ush* __restrict__ Wql,
    const ush* __restrict__ Wkh, const ush* __restrict__ Wkl,
    const float* __restrict__ bq, const float* __restrict__ bk,
    ush* __restrict__ qh, ush* __restrict__ ql,
    ush* __restrict__ kh, ush* __restrict__ kl) {
  __shared__ __align__(16) ush Ah[64][40], Al[64][40];
  __shared__ __align__(16) ush Bh[128][40], Bl[128][40];   // [n][k]
  const int tid = threadIdx.x;
  const int bx = blockIdx.x;
  const int wsel = bx >> 3;
  const int m0 = blockIdx.y * 64, n0 = (bx & 7) * 128;
  const ush* Bgh = wsel ? Wkh : Wqh;
  const ush* Bgl = wsel ? Wkl : Wql;
  const float* bias = wsel ? bk : bq;
  ush* oh = wsel ? kh : qh;
  ush* ol = wsel ? kl : ql;
  const int lane = tid & 63, wave = tid >> 6;
  const int wm = (wave >> 1) * 32, wn = (wave & 1) * 64;
  const int l15 = lane & 15, quad = lane >> 4;

  f32x4 acc[2][4];
#pragma unroll
  for (int i = 0; i < 2; i++)
#pragma unroll
    for (int j = 0; j < 4; j++) acc[i][j] = (f32x4){0.f, 0.f, 0.f, 0.f};

  for (int k0 = 0; k0 < 1024; k0 += 32) {
    {
      const int arow = tid >> 2, akc = (tid & 3) * 8;
      const size_t ga = (size_t)(m0 + arow) * 1024 + k0 + akc;
      *(uint4*)&Ah[arow][akc] = *(const uint4*)&xh[ga];
      *(uint4*)&Al[arow][akc] = *(const uint4*)&xl[ga];
    }
#pragma unroll
    for (int it = 0; it < 2; it++) {
      const int u = tid + 256 * it;
      const int brow = u >> 2, bkc = (u & 3) * 8;
      const size_t gb = (size_t)(n0 + brow) * 1024 + k0 + bkc;
      *(uint4*)&Bh[brow][bkc] = *(const uint4*)&Bgh[gb];
      *(uint4*)&Bl[brow][bkc] = *(const uint4*)&Bgl[gb];
    }
    __syncthreads();

    frag16 a_h[2], a_l[2], b_h[4], b_l[4];
#pragma unroll
    for (int s = 0; s < 2; s++) {
      const int row = wm + s * 16 + l15;
      a_h[s] = *(const frag16*)&Ah[row][quad * 8];
      a_l[s] = *(const frag16*)&Al[row][quad * 8];
    }
#pragma unroll
    for (int t = 0; t < 4; t++) {
      const int col = wn + t * 16 + l15;
      b_h[t] = *(const frag16*)&Bh[col][quad * 8];
      b_l[t] = *(const frag16*)&Bl[col][quad * 8];
    }
#pragma unroll
    for (int mi = 0; mi < 2; mi++)
#pragma unroll
      for (int ni = 0; ni < 4; ni++) {
        acc[mi][ni] = __builtin_amdgcn_mfma_f32_16x16x32_bf16(
            a_h[mi], b_h[ni], acc[mi][ni], 0, 0, 0);
        acc[mi][ni] = __builtin_amdgcn_mfma_f32_16x16x32_bf16(
            a_h[mi], b_l[ni], acc[mi][ni], 0, 0, 0);
        acc[mi][ni] = __builtin_amdgcn_mfma_f32_16x16x32_bf16(
            a_l[mi], b_h[ni], acc[mi][ni], 0, 0, 0);
      }
    __syncthreads();
  }

#pragma unroll
  for (int mi = 0; mi < 2; mi++) {
    const int rbase = m0 + wm + mi * 16 + quad * 4;
#pragma unroll
    for (int ni = 0; ni < 4; ni++) {
      const int col = n0 + wn + ni * 16 + l15;
      const float bv = bias[col];
      const int hidx = col >> 6, d = col & 63;
#pragma unroll
      for (int r = 0; r < 4; r++) {
        const int m = rbase + r;
        const int bb = m >> 10, ss = m & 1023;
        const size_t o = ((size_t)(bb * NH_ + hidx) * S_ + ss) * D_ + d;
        ush hh, ll;
        split2(acc[mi][ni][r] + bv, hh, ll);
        oh[o] = hh;
        ol[o] = ll;
      }
    }
  }
}

// ---------------------------------------------------------------------------
// Split-bf16 MFMA GEMM 64x128, copy staging (verified R13).
// EP 1 = bf16 [bh][s][d] (v); EP 2 = fp32 + residual (o-proj).
// ---------------------------------------------------------------------------
template <int EP>
__global__ __launch_bounds__(256) void gemm_mn(
    const ush* __restrict__ Abh, const ush* __restrict__ Abl,
    const ush* __restrict__ Bgh, const ush* __restrict__ Bgl,
    const float* __restrict__ bias, const float* __restrict__ resid,
    float* __restrict__ outf, ush* __restrict__ oh, ush* __restrict__ ol) {
  __shared__ __align__(16) ush Ah[64][40], Al[64][40];
  __shared__ __align__(16) ush Bh[128][40], Bl[128][40];
  const int tid = threadIdx.x;
  const int m0 = blockIdx.y * 64, n0 = blockIdx.x * 128;
  const int lane = tid & 63, wave = tid >> 6;
  const int wm = (wave >> 1) * 32, wn = (wave & 1) * 64;
  const int l15 = lane & 15, quad = lane >> 4;

  f32x4 acc[2][4];
#pragma unroll
  for (int i = 0; i < 2; i++)
#pragma unroll
    for (int j = 0; j < 4; j++) acc[i][j] = (f32x4){0.f, 0.f, 0.f, 0.f};

  for (int k0 = 0; k0 < 1024; k0 += 32) {
    {
      const int arow = tid >> 2, akc = (tid & 3) * 8;
      const size_t ga = (size_t)(m0 + arow) * 1024 + k0 + akc;
      *(uint4*)&Ah[arow][akc] = *(const uint4*)&Abh[ga];
      *(uint4*)&Al[arow][akc] = *(const uint4*)&Abl[ga];
    }
#pragma unroll
    for (int it = 0; it < 2; it++) {
      const int u = tid + 256 * it;
      const int brow = u >> 2, bkc = (u & 3) * 8;
      const size_t gb = (size_t)(n0 + brow) * 1024 + k0 + bkc;
      *(uint4*)&Bh[brow][bkc] = *(const uint4*)&Bgh[gb];
      *(uint4*)&Bl[brow][bkc] = *(const uint4*)&Bgl[gb];
    }
    __syncthreads();

    frag16 a_h[2], a_l[2], b_h[4], b_l[4];
#pragma unroll
    for (int s = 0; s < 2; s++) {
      const int row = wm + s * 16 + l15;
      a_h[s] = *(const frag16*)&Ah[row][quad * 8];
      a_l[s] = *(const frag16*)&Al[row][quad * 8];
    }
#pragma unroll
    for (int t = 0; t < 4; t++) {
      const int col = wn + t * 16 + l15;
      b_h[t] = *(const frag16*)&Bh[col][quad * 8];
      b_l[t] = *(const frag16*)&Bl[col][quad * 8];
    }
#pragma unroll
    for (int mi = 0; mi < 2; mi++)
#pragma unroll
      for (int ni = 0; ni < 4; ni++) {
        acc[mi][ni] = __builtin_amdgcn_mfma_f32_16x16x32_bf16(
            a_h[mi], b_h[ni], acc[mi][ni], 0, 0, 0);
        acc[mi][ni] = __builtin_amdgcn_mfma_f32_16x16x32_bf16(
            a_h[mi], b_l[ni], acc[mi][ni], 0, 0, 0);
        acc[mi][ni] = __builtin_amdgcn_mfma_f32_16x16x32_bf16(
            a_l[mi], b_h[ni], acc[mi][ni], 0, 0, 0);
      }
    __syncthreads();
  }

#pragma unroll
  for (int mi = 0; mi < 2; mi++) {
    const int rbase = m0 + wm + mi * 16 + quad * 4;
#pragma unroll
    for (int ni = 0; ni < 4; ni++) {
      const int col = n0 + wn + ni * 16 + l15;
      const float bv = bias[col];
      const int hidx = col >> 6, d = col & 63;
#pragma unroll
      for (int r = 0; r < 4; r++) {
        const int m = rbase + r;
        float val = acc[mi][ni][r] + bv;
        if (EP == 2) {
          outf[(size_t)m * 1024 + col] = val + resid[(size_t)m * 1024 + col];
        } else {
          const int bb = m >> 10, ss = m & 1023;
          const size_t o = ((size_t)(bb * NH_ + hidx) * S_ + ss) * D_ + d;
          oh[o] = bf16_rne(val);
        }
      }
    }
  }
}

// ---------------------------------------------------------------------------
// V transpose (verified R10).
// ---------------------------------------------------------------------------
__global__ __launch_bounds__(256) void transpose_v(
    const ush* __restrict__ vbf, ush* __restrict__ vT) {
  __shared__ __align__(16) ush Ls[64][72];
  const int tid = threadIdx.x;
  const int s0 = blockIdx.x * 64, bh = blockIdx.y;
#pragma unroll
  for (int it = 0; it < 2; it++) {
    int flat = tid + 256 * it;
    int row = flat >> 3, dc = (flat & 7) * 8;
    *(uint4*)&Ls[row][dc] =
        *(const uint4*)&vbf[((size_t)bh * S_ + s0 + row) * D_ + dc];
  }
  __syncthreads();
#pragma unroll
  for (int it = 0; it < 2; it++) {
    int flat = tid + 256 * it;
    int drow = flat >> 3, sc = (flat & 7) * 8;
    ush v8[8];
#pragma unroll
    for (int u = 0; u < 8; u++) v8[u] = Ls[sc + u][drow];
    uint4 p;
    p.x = v8[0] | ((unsigned)v8[1] << 16); p.y = v8[2] | ((unsigned)v8[3] << 16);
    p.z = v8[4] | ((unsigned)v8[5] << 16); p.w = v8[6] | ((unsigned)v8[7] << 16);
    *(uint4*)&vT[((size_t)bh * D_ + drow) * S_ + s0 + sc] = p;
  }
}

// ---------------------------------------------------------------------------
// MFMA flash attention v3: fixed-max softmax (M=20) + SPLIT-P (2^-17 P error,
// restores argmax margin) with V B-frags loaded DIRECTLY FROM GLOBAL vT
// (drops VTs from LDS -> 4 arrays = 36,864 B -> 4 blocks/CU, avoiding R12's
// occupancy collapse). PV MFMA order = R12 verbatim (ctx bitwise = R12).
// ---------------------------------------------------------------------------
__global__ __launch_bounds__(256) void attn3(
    const ush* __restrict__ qh, const ush* __restrict__ ql,
    const ush* __restrict__ kh, const ush* __restrict__ kl,
    const ush* __restrict__ vT,
    ush* __restrict__ ch, ush* __restrict__ cl) {
  __shared__ __align__(16) ush Kh[64][72], Kl[64][72];
  __shared__ __align__(16) ush Psth[64][72];   // [m][j] P hi
  __shared__ __align__(16) ush Pstl[64][72];   // [m][j] P lo
  const int tid = threadIdx.x;
  const int lane = tid & 63, wave = tid >> 6;
  const int l15 = lane & 15, quad = lane >> 4;
  const int w16 = wave * 16;
  const int bh = blockIdx.y;
  const int b = bh >> 4, h = bh & 15;
  const int q0 = blockIdx.x * 64;

  const size_t qrow = ((size_t)bh * S_ + q0 + w16 + l15) * D_;
  frag16 a_h[2], a_l[2];
  a_h[0] = *(const frag16*)&qh[qrow + quad * 8];
  a_h[1] = *(const frag16*)&qh[qrow + 32 + quad * 8];
  a_l[0] = *(const frag16*)&ql[qrow + quad * 8];
  a_l[1] = *(const frag16*)&ql[qrow + 32 + quad * 8];

  f32x4 o[4];
  float lrow[4];
#pragma unroll
  for (int i = 0; i < 4; i++) {
    o[i] = (f32x4){0.f, 0.f, 0.f, 0.f};
    lrow[i] = 0.f;
  }

  const size_t kbase = (size_t)bh * S_ * D_;
  const size_t vbase = (size_t)bh * D_ * S_;
  for (int j0 = 0; j0 < S_; j0 += 64) {
    __syncthreads();
#pragma unroll
    for (int it = 0; it < 2; it++) {
      const int flat = tid + 256 * it;
      const int row = flat >> 3, dc = (flat & 7) * 8;
      const size_t gk = kbase + (size_t)(j0 + row) * D_ + dc;
      *(uint4*)&Kh[row][dc] = *(const uint4*)&kh[gk];
      *(uint4*)&Kl[row][dc] = *(const uint4*)&kl[gk];
    }
    __syncthreads();

    // ---- S = Q.K^T (3-term split) ----
    f32x4 c4[4];
#pragma unroll
    for (int nt = 0; nt < 4; nt++) c4[nt] = (f32x4){0.f, 0.f, 0.f, 0.f};
#pragma unroll
    for (int kk = 0; kk < 2; kk++) {
#pragma unroll
      for (int nt = 0; nt < 4; nt++) {
        frag16 bh_ = *(const frag16*)&Kh[nt * 16 + l15][kk * 32 + quad * 8];
        frag16 bl_ = *(const frag16*)&Kl[nt * 16 + l15][kk * 32 + quad * 8];
        c4[nt] = __builtin_amdgcn_mfma_f32_16x16x32_bf16(a_h[kk], bh_, c4[nt], 0, 0, 0);
        c4[nt] = __builtin_amdgcn_mfma_f32_16x16x32_bf16(a_l[kk], bh_, c4[nt], 0, 0, 0);
        c4[nt] = __builtin_amdgcn_mfma_f32_16x16x32_bf16(a_h[kk], bl_, c4[nt], 0, 0, 0);
      }
    }

    // ---- bias + fixed-max exp + split-P store ----
    const bool far = (j0 >= q0 + 68) || (q0 >= j0 + 68);
#pragma unroll
    for (int r = 0; r < 4; r++) {
      const int qi = q0 + w16 + quad * 4 + r;
#pragma unroll
      for (int nt = 0; nt < 4; nt++) {
        const int jj = j0 + nt * 16 + l15;
        const float dist = fabsf((float)(qi - jj));
        const float pb = far ? 0.60653066f : __expf(-0.1f * fminf(dist, 5.0f));
        const float sv =
            __expf((c4[nt][r] + pb) * 0.125f - 0.1f * dist - 20.0f);
        lrow[r] += sv;
        ush hh, ll;
        split2(sv, hh, ll);
        Psth[w16 + quad * 4 + r][nt * 16 + l15] = hh;
        Pstl[w16 + quad * 4 + r][nt * 16 + l15] = ll;
      }
    }

    // ---- PV split; V frags direct from global vT ----
    frag16 pah[2], pal[2];
#pragma unroll
    for (int kk = 0; kk < 2; kk++) {
      pah[kk] = *(const frag16*)&Psth[w16 + l15][kk * 32 + quad * 8];
      pal[kk] = *(const frag16*)&Pstl[w16 + l15][kk * 32 + quad * 8];
    }
#pragma unroll
    for (int dt = 0; dt < 4; dt++) {
      const ush* vg = &vT[vbase + (size_t)(dt * 16 + l15) * S_ + j0 + quad * 8];
      frag16 vb0 = *(const frag16*)vg;
      frag16 vb1 = *(const frag16*)(vg + 32);
      o[dt] = __builtin_amdgcn_mfma_f32_16x16x32_bf16(pah[0], vb0, o[dt], 0, 0, 0);
      o[dt] = __builtin_amdgcn_mfma_f32_16x16x32_bf16(pal[0], vb0, o[dt], 0, 0, 0);
      o[dt] = __builtin_amdgcn_mfma_f32_16x16x32_bf16(pah[1], vb1, o[dt], 0, 0, 0);
      o[dt] = __builtin_amdgcn_mfma_f32_16x16x32_bf16(pal[1], vb1, o[dt], 0, 0, 0);
    }
  }

  // ---- deferred row-sum + normalize + pre-split ctx ----
#pragma unroll
  for (int r = 0; r < 4; r++) {
#pragma unroll
    for (int off = 1; off < 16; off <<= 1) lrow[r] += __shfl_xor(lrow[r], off);
    const float inv = 1.0f / lrow[r];
    const size_t rowp =
        ((size_t)(b * S_ + q0 + w16 + quad * 4 + r)) * H_ + h * 64;
#pragma unroll
    for (int dt = 0; dt < 4; dt++) {
      ush hh, ll;
      split2(o[dt][r] * inv, hh, ll);
      ch[rowp + dt * 16 + l15] = hh;
      cl[rowp + dt * 16 + l15] = ll;
    }
  }
}

// ---------------------------------------------------------------------------
// Ws transpose: Ws [1024][9] -> WsT [9][1024]. Grid 36.
// ---------------------------------------------------------------------------
__global__ __launch_bounds__(256) void transpose_ws(
    const float* __restrict__ Ws, float* __restrict__ WsT) {
  const int idx = blockIdx.x * 256 + threadIdx.x;   // 0..9215
  if (idx < 9216) {
    const int hh = idx / 9, l = idx % 9;
    WsT[l * 1024 + hh] = Ws[idx];
  }
}

// ---------------------------------------------------------------------------
// Fused LayerNorm + span logits, ONE WAVE PER ROW (no cross-wave reduce, no
// barriers; 66 DS wave-ops/row vs 264). WsT gives coalesced weight reads.
// ---------------------------------------------------------------------------
__global__ __launch_bounds__(256) void ln_span2(
    const float* __restrict__ y, const float* __restrict__ g,
    const float* __restrict__ bta, const float* __restrict__ WsT,
    const float* __restrict__ bs, float* __restrict__ logits) {
  const int tid = threadIdx.x, lane = tid & 63, wave = tid >> 6;
  const int row = blockIdx.x * 4 + wave;
  const float* yr = y + (size_t)row * 1024;
  float vals[16], s = 0.f, s2 = 0.f;
#pragma unroll
  for (int i = 0; i < 16; i++) {
    float t = yr[lane + i * 64];
    vals[i] = t; s += t; s2 += t * t;
  }
#pragma unroll
  for (int off = 32; off; off >>= 1) {
    s += __shfl_xor(s, off);
    s2 += __shfl_xor(s2, off);
  }
  const float mu = s * (1.0f / 1024.0f);
  const float var = s2 * (1.0f / 1024.0f) - mu * mu;
  const float inv = rsqrtf(var + 1e-5f);

  float lg[9];
#pragma unroll
  for (int l = 0; l < 9; l++) lg[l] = 0.f;
#pragma unroll
  for (int i = 0; i < 16; i++) {
    const int hh = lane + i * 64;
    const float yn = (vals[i] - mu) * inv * g[hh] + bta[hh];
#pragma unroll
    for (int l = 0; l < 9; l++) lg[l] += yn * WsT[l * 1024 + hh];
  }
#pragma unroll
  for (int l = 0; l < 9; l++) {
#pragma unroll
    for (int off = 32; off; off >>= 1) lg[l] += __shfl_xor(lg[l], off);
  }
  if (lane < 9) logits[(size_t)row * 9 + lane] = lg[lane] + bs[lane];
}

// ---------------------------------------------------------------------------
// Entity-bias adjustment + FP32 output. One thread per token.
// ---------------------------------------------------------------------------
__global__ __launch_bounds__(256) void final_kernel(
    const float* __restrict__ logits, const float* __restrict__ eb,
    float* __restrict__ out) {
  const int m = blockIdx.x * 256 + threadIdx.x;
  const int i = m & 1023;
  float cur[9];
#pragma unroll
  for (int l = 0; l < 9; l++) cur[l] = logits[(size_t)m * 9 + l];
  if (i > 0) {
    const float* prev = logits + (size_t)(m - 1) * 9;
    int am = 0;
    float best = prev[0];
#pragma unroll
    for (int l = 1; l < 9; l++) {
      float pv = prev[l];
      if (pv > best) { best = pv; am = l; }  // strict > == first-max argmax
    }
    if (am == 1) cur[2] += 2.0f * eb[2];
  }
#pragma unroll
  for (int l = 0; l < 9; l++) out[(size_t)m * 9 + l] = cur[l];
}

// ---------------------------------------------------------------------------
extern "C" void kernel_launch(void* const* d_in, const int* in_sizes, int n_in,
                              void* d_out, int out_size, void* d_ws, size_t ws_size,
                              hipStream_t stream) {
  const float* x    = (const float*)d_in[0];
  const float* Wq   = (const float*)d_in[1];
  const float* bq   = (const float*)d_in[2];
  const float* Wk   = (const float*)d_in[3];
  const float* bk   = (const float*)d_in[4];
  const float* Wv   = (const float*)d_in[5];
  const float* bv   = (const float*)d_in[6];
  const float* Wo   = (const float*)d_in[7];
  const float* bo   = (const float*)d_in[8];
  const float* ln_g = (const float*)d_in[9];
  const float* ln_b = (const float*)d_in[10];
  const float* Ws   = (const float*)d_in[11];
  const float* bs   = (const float*)d_in[12];
  const float* eb   = (const float*)d_in[13];
  float* out = (float*)d_out;       // output fp32 (verified R5)
  char* W8 = (char*)d_ws;

  // ---- ws layout, 64 MB envelope with phase-aliasing (R13-proven) ----
  ush* WoT_h = (ush*)(W8 + 0 * MB_);
  ush* WoT_l = (ush*)(W8 + 2 * MB_);
  ush* WqT_h = (ush*)(W8 + 4 * MB_);
  ush* WqT_l = (ush*)(W8 + 6 * MB_);
  ush* WkT_h = (ush*)(W8 + 8 * MB_);
  ush* WkT_l = (ush*)(W8 + 10 * MB_);
  ush* WvT_h = (ush*)(W8 + 12 * MB_);
  ush* WvT_l = (ush*)(W8 + 14 * MB_);
  ush* xh    = (ush*)(W8 + 16 * MB_);
  ush* xl    = (ush*)(W8 + 24 * MB_);
  ush* qh    = (ush*)(W8 + 32 * MB_);
  ush* ql    = (ush*)(W8 + 40 * MB_);
  ush* kh    = (ush*)(W8 + 48 * MB_);
  ush* kl    = (ush*)(W8 + 56 * MB_);
  // aliases:
  ush*   vbf   = (ush*)(W8 + 4 * MB_);    // over WqT+WkT (dead after qk-gemm)
  ush*   vT    = (ush*)(W8 + 16 * MB_);   // over xh (dead after v-gemm)
  ush*   ctxh  = (ush*)(W8 + 24 * MB_);   // over xl (dead)
  ush*   ctxl  = (ush*)(W8 + 4 * MB_);    // over vbf (dead after transpose)
  float* y_ws  = (float*)(W8 + 32 * MB_); // over qh/ql (dead after attn)
  float* lg_ws = (float*)(W8 + 48 * MB_); // over kh (dead after attn)
  float* WsT   = (float*)(W8 + 56 * MB_); // over kl (dead after attn)

  split_wT4<<<dim3(16, 16, 4), 256, 0, stream>>>(
      Wq, Wk, Wv, Wo, WqT_h, WqT_l, WkT_h, WkT_l, WvT_h, WvT_l, WoT_h, WoT_l);
  split_x<<<2048, 256, 0, stream>>>(x, xh, xl);

  gemm_qk<<<dim3(16, 64), 256, 0, stream>>>(xh, xl, WqT_h, WqT_l, WkT_h, WkT_l,
                                            bq, bk, qh, ql, kh, kl);
  gemm_mn<1><<<dim3(8, 64), 256, 0, stream>>>(xh, xl, WvT_h, WvT_l,
                                              bv, nullptr, nullptr, vbf, nullptr);
  transpose_v<<<dim3(16, 64), 256, 0, stream>>>(vbf, vT);
  attn3<<<dim3(16, 64), 256, 0, stream>>>(qh, ql, kh, kl, vT, ctxh, ctxl);
  gemm_mn<2><<<dim3(8, 64), 256, 0, stream>>>(ctxh, ctxl, WoT_h, WoT_l,
                                              bo, x, y_ws, nullptr, nullptr);
  transpose_ws<<<36, 256, 0, stream>>>(Ws, WsT);
  ln_span2<<<1024, 256, 0, stream>>>(y_ws, ln_g, ln_b, WsT, bs, lg_ws);
  final_kernel<<<16, 256, 0, stream>>>(lg_ws, eb, out);
}